// Round 8
// baseline (227.456 us; speedup 1.0000x reference)
//
#include <hip/hip_runtime.h>
#include <hip/hip_bf16.h>

#define NS 100000
#define CC 64
#define K3 27
#define EPSV 1e-4f
#define NBLK 3125     // 32-site tiles
#define PACKB 108     // weight-pack blocks

typedef __attribute__((ext_vector_type(4))) float f32x4;
typedef __attribute__((ext_vector_type(8))) short bf16x8;

// round-to-nearest-even f32 -> bf16 bits
__device__ __forceinline__ short f2bf(float f) {
    union { float f; unsigned u; } uf; uf.f = f;
    unsigned r = (uf.u + 0x7fffu + ((uf.u >> 16) & 1u)) >> 16;
    return (short)r;
}

// ---- prepare: blocks [0,NBLK) do BN1+ReLU->bf16 X1 (+ zero rows);
//      blocks [NBLK,NBLK+PACKB) pack W1/W2 into MFMA B-fragments. ----
// B-fragment fi = k*8 + kc*4 + t4; lane l holds 8 contiguous-k elements
// B[kc*32 + 8*(l>>4) + j][t4*16 + (l&15)], stored at (fi*64+l)*8.
__global__ __launch_bounds__(256) void prepare(
    const float* __restrict__ x,
    const float* __restrict__ g1, const float* __restrict__ b1,
    const float* __restrict__ m1, const float* __restrict__ v1,
    const float* __restrict__ W1, const float* __restrict__ W2,
    short* __restrict__ X1, short* __restrict__ X2,
    short* __restrict__ Wp1, short* __restrict__ Wp2)
{
    int blk = blockIdx.x;
    if (blk < NBLK) {
        int tid = blk * 256 + threadIdx.x;        // NS*8 threads, one per 8 channels
        int ch8 = (tid & 7) * 8;
        float4 ga = *(const float4*)(g1 + ch8), gb = *(const float4*)(g1 + ch8 + 4);
        float4 ba = *(const float4*)(b1 + ch8), bb = *(const float4*)(b1 + ch8 + 4);
        float4 ma = *(const float4*)(m1 + ch8), mb = *(const float4*)(m1 + ch8 + 4);
        float4 va = *(const float4*)(v1 + ch8), vb = *(const float4*)(v1 + ch8 + 4);
        float g[8] = {ga.x,ga.y,ga.z,ga.w,gb.x,gb.y,gb.z,gb.w};
        float b[8] = {ba.x,ba.y,ba.z,ba.w,bb.x,bb.y,bb.z,bb.w};
        float m[8] = {ma.x,ma.y,ma.z,ma.w,mb.x,mb.y,mb.z,mb.w};
        float vv[8] = {va.x,va.y,va.z,va.w,vb.x,vb.y,vb.z,vb.w};
        const float* px = x + (long)tid * 8;
        float4 u = *(const float4*)px;
        float4 w = *(const float4*)(px + 4);
        float o[8] = {u.x,u.y,u.z,u.w,w.x,w.y,w.z,w.w};
        bf16x8 r;
#pragma unroll
        for (int j = 0; j < 8; ++j) {
            float s = g[j] * rsqrtf(vv[j] + EPSV);
            float bi = b[j] - m[j] * s;
            r[j] = f2bf(fmaxf(fmaf(o[j], s, bi), 0.f));
        }
        *(bf16x8*)(X1 + (long)tid * 8) = r;
        if (blk == 0 && threadIdx.x < 64) {       // zero "missing neighbor" row
            X1[(long)NS * 64 + threadIdx.x] = 0;
            X2[(long)NS * 64 + threadIdx.x] = 0;
        }
    } else {
        int t = (blk - NBLK) * 256 + threadIdx.x; // 2*27*8*64 = 27648 threads
        if (t >= 2 * K3 * 8 * 64) return;
        int lane = t & 63;
        int f = t >> 6;
        int which = f / (K3 * 8);
        int f2 = f % (K3 * 8);
        int k = f2 >> 3, kc = (f2 >> 2) & 1, t4 = f2 & 3;
        const float* W = which ? W2 : W1;
        short* Wp = which ? Wp2 : Wp1;
        int col = t4 * 16 + (lane & 15);
        int kr0 = kc * 32 + 8 * (lane >> 4);
        bf16x8 v;
#pragma unroll
        for (int j = 0; j < 8; ++j) v[j] = f2bf(W[(k * CC + kr0 + j) * CC + col]);
        *(bf16x8*)(Wp + ((long)f2 * 64 + lane) * 8) = v;
    }
}

// ---- conv: block = one 32-site tile; 4 waves k-split the 27 offsets
// (k = w + 4j). ALL 28 A-fragments are loaded into registers up front
// (batched MLP: ~330 outstanding gathers/CU), then the MFMA phase runs.
// Partial sums combined via LDS. PHASE 1: BN2+ReLU -> bf16 X2.
// PHASE 2: +features -> f32 out. ----
template <int PHASE>
__global__ __launch_bounds__(256, 2) void subm_conv(
    const short* __restrict__ Xg,     // (NS+1) x 64 bf16, row NS zeros
    const int* __restrict__ nb,
    const short* __restrict__ Wp,
    const float* __restrict__ g2, const float* __restrict__ b2,
    const float* __restrict__ m2, const float* __restrict__ v2,
    const float* __restrict__ feat,
    short* __restrict__ Xout, float* __restrict__ yout)
{
    __shared__ float red[4][32][64];       // 32 KB partial sums
    __shared__ float s2c[64], b2c[64];     // PHASE1 BN2 coeffs
    int lane = threadIdx.x & 63;
    int w = threadIdx.x >> 6;
    int base = blockIdx.x * 32;
    int r15 = lane & 15, hi = lane >> 4;
    int site0 = base + r15, site1 = base + 16 + r15;

    if (PHASE == 1 && threadIdx.x < 64) {
        float s = g2[threadIdx.x] * rsqrtf(v2[threadIdx.x] + EPSV);
        s2c[threadIdx.x] = s;
        b2c[threadIdx.x] = b2[threadIdx.x] - m2[threadIdx.x] * s;
    }

    // ---- phase A: all neighbor indices (14 independent loads) ----
    int q0[7], q1[7];
#pragma unroll
    for (int j = 0; j < 7; ++j) {
        int k = w + 4 * j;
        int i0 = (k < K3) ? nb[site0 * K3 + k] : -1;
        int i1 = (k < K3) ? nb[site1 * K3 + k] : -1;
        q0[j] = (i0 < 0) ? NS : i0;
        q1[j] = (i1 < 0) ? NS : i1;
    }

    // ---- phase B: ALL 28 A-fragment gathers issued before any use ----
    bf16x8 A00[7], A01[7], A10[7], A11[7];
#pragma unroll
    for (int j = 0; j < 7; ++j) {
        const short* p0 = Xg + (long)q0[j] * 64 + hi * 8;
        const short* p1 = Xg + (long)q1[j] * 64 + hi * 8;
        A00[j] = *(const bf16x8*)p0;
        A01[j] = *(const bf16x8*)(p0 + 32);
        A10[j] = *(const bf16x8*)p1;
        A11[j] = *(const bf16x8*)(p1 + 32);
    }

    // ---- phase C: MFMA over the wave's 7 offsets ----
    f32x4 acc[2][4] = {};
    const bf16x8* wpv = (const bf16x8*)Wp;
#pragma unroll
    for (int j = 0; j < 7; ++j) {
        int k = w + 4 * j;
        int kk = (k < K3) ? k : 0;         // safe B addr; A is zero row when padded
        const bf16x8* bp = wpv + (long)kk * 8 * 64 + lane;
#pragma unroll
        for (int t4 = 0; t4 < 4; ++t4) {
            bf16x8 b0 = bp[t4 * 64];
            bf16x8 b1 = bp[(4 + t4) * 64];
            acc[0][t4] = __builtin_amdgcn_mfma_f32_16x16x32_bf16(A00[j], b0, acc[0][t4], 0, 0, 0);
            acc[1][t4] = __builtin_amdgcn_mfma_f32_16x16x32_bf16(A10[j], b0, acc[1][t4], 0, 0, 0);
            acc[0][t4] = __builtin_amdgcn_mfma_f32_16x16x32_bf16(A01[j], b1, acc[0][t4], 0, 0, 0);
            acc[1][t4] = __builtin_amdgcn_mfma_f32_16x16x32_bf16(A11[j], b1, acc[1][t4], 0, 0, 0);
        }
    }

    // C/D layout (m89): col = t4*16 + (lane&15), row = mt*16 + (lane>>4)*4 + r
#pragma unroll
    for (int mt = 0; mt < 2; ++mt)
#pragma unroll
        for (int t4 = 0; t4 < 4; ++t4)
#pragma unroll
            for (int r = 0; r < 4; ++r)
                red[w][mt * 16 + hi * 4 + r][t4 * 16 + r15] = acc[mt][t4][r];
    __syncthreads();

    int t = threadIdx.x;
    int lr = t >> 3, c0 = (t & 7) * 8;
    int row = base + lr;
    float s[8];
#pragma unroll
    for (int c = 0; c < 8; ++c)
        s[c] = red[0][lr][c0 + c] + red[1][lr][c0 + c] +
               red[2][lr][c0 + c] + red[3][lr][c0 + c];
    if (PHASE == 1) {
        bf16x8 o;
#pragma unroll
        for (int c = 0; c < 8; ++c)
            o[c] = f2bf(fmaxf(fmaf(s[c], s2c[c0 + c], b2c[c0 + c]), 0.f));
        *(bf16x8*)(Xout + (long)row * 64 + c0) = o;
    } else {
        const float* fp = feat + (long)row * 64 + c0;
        float4 f0 = *(const float4*)fp, f1 = *(const float4*)(fp + 4);
        float4 o0 = {s[0] + f0.x, s[1] + f0.y, s[2] + f0.z, s[3] + f0.w};
        float4 o1 = {s[4] + f1.x, s[5] + f1.y, s[6] + f1.z, s[7] + f1.w};
        float* op = yout + (long)row * 64 + c0;
        *(float4*)op = o0;
        *(float4*)(op + 4) = o1;
    }
}

extern "C" void kernel_launch(void* const* d_in, const int* in_sizes, int n_in,
                              void* d_out, int out_size, void* d_ws, size_t ws_size,
                              hipStream_t stream) {
    const float* feat = (const float*)d_in[0];
    const int*   nb   = (const int*)d_in[1];
    const float* g1 = (const float*)d_in[2];
    const float* b1 = (const float*)d_in[3];
    const float* m1 = (const float*)d_in[4];
    const float* v1 = (const float*)d_in[5];
    const float* W1 = (const float*)d_in[6];
    const float* g2 = (const float*)d_in[7];
    const float* b2 = (const float*)d_in[8];
    const float* m2 = (const float*)d_in[9];
    const float* v2 = (const float*)d_in[10];
    const float* W2 = (const float*)d_in[11];
    float* out = (float*)d_out;

    // ws layout: X1 (NS+16)*64 bf16 = 12,802,048 B; X2 same; Wp1/Wp2 221,184 B each
    char* ws = (char*)d_ws;
    short* X1 = (short*)ws;
    short* X2 = (short*)(ws + 12802048);
    short* Wp1 = (short*)(ws + 25604096);
    short* Wp2 = (short*)(ws + 25604096 + 221184);

    prepare<<<NBLK + PACKB, 256, 0, stream>>>(feat, g1, b1, m1, v1, W1, W2,
                                              X1, X2, Wp1, Wp2);
    subm_conv<1><<<NBLK, 256, 0, stream>>>(X1, nb, Wp1, g2, b2, m2, v2,
                                           nullptr, X2, nullptr);
    subm_conv<2><<<NBLK, 256, 0, stream>>>(X2, nb, Wp2, g2, b2, m2, v2,
                                           feat, nullptr, out);
}